// Round 24
// baseline (266.405 us; speedup 1.0000x reference)
//
#include <hip/hip_runtime.h>
#include <stdint.h>

#define N_NODES 100000
#define N_EDGES 600000
#define DIM_H   128
#define DIM_OUT 64
#define WPAD    136      // padded LDS row stride in ushort units (272B)
#define BN_EPS  1e-5f
#define NBLK    391      // ceil(N_NODES/256)
#define GRID64_HEAD 1563 // ceil(N_NODES/64)
#define MLP_GRID 782     // 128 rows/block
#define GATHER_GRID 6250 // 16 nodes/block (4 waves x 4 nodes)

typedef __attribute__((ext_vector_type(8))) __bf16        bh8;
typedef __attribute__((ext_vector_type(4))) float         fl4;
typedef __attribute__((ext_vector_type(8))) unsigned short us8;
typedef __attribute__((ext_vector_type(4))) unsigned short us4;

__device__ __forceinline__ unsigned short f2bfbits(float f) {
  unsigned int u = __builtin_bit_cast(unsigned int, f);
  u += 0x7fffu + ((u >> 16) & 1u);           // RNE
  return (unsigned short)(u >> 16);
}
__device__ __forceinline__ float bf2f(unsigned short b) {
  unsigned int u = ((unsigned int)b) << 16;
  return __builtin_bit_cast(float, u);
}
// in-wave LDS producer->consumer fence (lanes of the same wave only)
__device__ __forceinline__ void wave_lds_fence() {
  asm volatile("s_waitcnt lgkmcnt(0)" ::: "memory");
  __builtin_amdgcn_sched_barrier(0);
}

// ---------------- weight prep (fragment-linear layout) + zero stats/deg/dummy row ----------------
__global__ void prep_kernel(const float* __restrict__ cw1, const float* __restrict__ cw2,
                            const float* __restrict__ fc1w, const float* __restrict__ fc2w,
                            unsigned short* __restrict__ W1F, unsigned short* __restrict__ W2F,
                            unsigned short* __restrict__ F1F, unsigned short* __restrict__ F2F,
                            float* __restrict__ stats, int* __restrict__ deg,
                            unsigned short* __restrict__ zrow) {
  int t = blockIdx.x * 256 + threadIdx.x;
  if (t < 3 * 16384) {
    int l = t >> 14, o = t & 16383;
    int j = o & 7, lane = (o >> 3) & 63, kk = (o >> 9) & 3, n0 = o >> 11;
    int k = kk * 32 + ((lane >> 4) << 3) + j;
    int n = (n0 << 4) + (lane & 15);
    W1F[t] = f2bfbits(cw1[l * 16384 + k * 128 + n]);
    W2F[t] = f2bfbits(cw2[l * 16384 + k * 128 + n]);
  }
  if (t < 16384) {
    int o = t;
    int j = o & 7, lane = (o >> 3) & 63, kk = (o >> 9) & 3, n0 = o >> 11;
    int k = kk * 32 + ((lane >> 4) << 3) + j;
    int n = (n0 << 4) + (lane & 15);
    F1F[t] = f2bfbits(fc1w[k * 128 + n]);
  }
  if (t < 8192) {
    int o = t;
    int j = o & 7, lane = (o >> 3) & 63, kk = (o >> 9) & 3, n0 = o >> 11;
    int k = kk * 32 + ((lane >> 4) << 3) + j;
    int n = (n0 << 4) + (lane & 15);                 // n < 64
    F2F[t] = f2bfbits(fc2w[k * 64 + n]);
  }
  if (t < 6144)  stats[t] = 0.f;                     // 3 layers x 8 replicas x 256
  if (t < 128)   zrow[t] = 0;                        // dummy zero row at H[N_NODES]
  if (t < N_NODES) deg[t] = 0;
}

// ---------------- x->bf16 cast + degree count (no mask packing) ----------------
__global__ void deg_xcast(const float* __restrict__ x, unsigned short* __restrict__ xB,
                          const int* __restrict__ ei, int* __restrict__ deg) {
  int i = blockIdx.x * 256 + threadIdx.x;    // 3.2M fl4 chunks exactly
  fl4 v = reinterpret_cast<const fl4*>(x)[i];
  us4 p;
#pragma unroll
  for (int j = 0; j < 4; ++j) p[j] = f2bfbits(v[j]);
  reinterpret_cast<us4*>(xB)[i] = p;
  if (i < N_EDGES) atomicAdd(&deg[ei[N_EDGES + i]], 1);
}

// ---------------- CSR build ----------------
__global__ void scanA(const int* __restrict__ deg, int* __restrict__ rowstart,
                      int* __restrict__ bsum) {
  __shared__ int s[256];
  int t = threadIdx.x, i = blockIdx.x * 256 + t;
  int v = (i < N_NODES) ? deg[i] : 0;
  s[t] = v;
  __syncthreads();
#pragma unroll
  for (int off = 1; off < 256; off <<= 1) {
    int u = (t >= off) ? s[t - off] : 0;
    __syncthreads();
    s[t] += u;
    __syncthreads();
  }
  if (i < N_NODES) rowstart[i] = s[t] - v;
  if (t == 0) bsum[blockIdx.x] = s[255];
}

// scanC with inline block-offset computation
__global__ void scanC(int* __restrict__ rowstart, const int* __restrict__ bsum,
                      int* __restrict__ cursor) {
  __shared__ int sred[256];
  int b = blockIdx.x, t = threadIdx.x;
  int partial = 0;
  for (int j = t; j < b; j += 256) partial += bsum[j];
  sred[t] = partial;
  __syncthreads();
#pragma unroll
  for (int off = 128; off > 0; off >>= 1) {
    if (t < off) sred[t] += sred[t + off];
    __syncthreads();
  }
  int boffb = sred[0];
  int i = b * 256 + t;
  if (i < N_NODES) {
    int v = rowstart[i] + boffb;
    rowstart[i] = v;
    cursor[i] = v;
  }
  if (i == 0) rowstart[N_NODES] = N_EDGES;
}

__global__ void csr_fill(const int* __restrict__ ei, int* __restrict__ cursor,
                         int* __restrict__ csr_src) {
  int e = blockIdx.x * 256 + threadIdx.x;
  if (e < N_EDGES) {
    int pos = atomicAdd(&cursor[ei[N_EDGES + e]], 1);
    csr_src[pos] = ei[e];
  }
}

// ---------------- BN finalize (sums 8 stat replicas) ----------------
__global__ void bn_finalize(const float* __restrict__ stats, const float* __restrict__ gamma,
                            const float* __restrict__ beta, float* __restrict__ sb) {
  int c = threadIdx.x;
  float s = 0.f, ss = 0.f;
#pragma unroll
  for (int r = 0; r < 8; ++r) {
    s  += stats[r * 256 + c];
    ss += stats[r * 256 + 128 + c];
  }
  const float inv_n = 1.0f / (float)N_NODES;
  float mean = s * inv_n;
  float var  = ss * inv_n - mean * mean;
  float sc = gamma[c] * rsqrtf(var + BN_EPS);
  sb[c] = sc;
  sb[128 + c] = beta[c] - mean * sc;
}

// ---------------- gather: FOUR nodes per wave, one per quarter; no cross-quarter reduce ----------
template <int AFFINE>
__global__ __launch_bounds__(256)
void gather_h(const unsigned short* __restrict__ H, const float* __restrict__ sb,
              const int* __restrict__ rowstart, const int* __restrict__ csr,
              unsigned short* __restrict__ aggB) {
  int wbase = (blockIdx.x * 4 + (threadIdx.x >> 6)) * 4;  // 6250*4*4 == N_NODES exactly
  int lane = threadIdx.x & 63;
  int q = lane >> 4, lc = lane & 15;
  int c = lc * 8;                        // 8 bf16 cols/lane; 16 lanes cover the row

  fl4 scA, scB, bcA, bcB;
  if (AFFINE) {
    scA = *reinterpret_cast<const fl4*>(sb + c);
    scB = *reinterpret_cast<const fl4*>(sb + c + 4);
    bcA = *reinterpret_cast<const fl4*>(sb + 128 + c);
    bcB = *reinterpret_cast<const fl4*>(sb + 128 + c + 4);
  }

  int nq = wbase + q;                    // this quarter's node (uniform within quarter)
  int rs = rowstart[nq], re = rowstart[nq + 1];
  int cnt = re - rs + 1;                 // {self} + neighbors
  int cmax = cnt;                        // wave-uniform loop bound = max over 4 quarters
  cmax = max(cmax, __shfl_xor(cmax, 16));
  cmax = max(cmax, __shfl_xor(cmax, 32));

  float acc[8] = {0.f, 0.f, 0.f, 0.f, 0.f, 0.f, 0.f, 0.f};

  for (int base = 0; base < cmax; base += 16) {
    int item = base + lc;
    int myidx = (item == 0) ? nq
              : ((item < cnt) ? csr[rs + item - 1] : N_NODES);  // dummy zero row
    int lim = cmax - base; if (lim > 16) lim = 16;
    for (int m = 0; m < lim; m += 4) {   // 4 rows in flight per quarter (16 per wave)
      int i0 = __shfl(myidx, (q << 4) + m);
      int i1 = __shfl(myidx, (q << 4) + m + 1);
      int i2 = __shfl(myidx, (q << 4) + m + 2);
      int i3 = __shfl(myidx, (q << 4) + m + 3);
      us8 r0 = *reinterpret_cast<const us8*>(H + (long)i0 * DIM_H + c);
      us8 r1 = *reinterpret_cast<const us8*>(H + (long)i1 * DIM_H + c);
      us8 r2 = *reinterpret_cast<const us8*>(H + (long)i2 * DIM_H + c);
      us8 r3 = *reinterpret_cast<const us8*>(H + (long)i3 * DIM_H + c);
#pragma unroll
      for (int j = 0; j < 8; ++j)
        acc[j] += (bf2f(r0[j]) + bf2f(r1[j])) + (bf2f(r2[j]) + bf2f(r3[j]));
    }
  }

  // direct store: every lane stores its 8 cols of its quarter's node
  us8 pk;
  if (AFFINE) {
    float fc = (float)cnt;
#pragma unroll
    for (int j = 0; j < 4; ++j) {
      pk[j]     = f2bfbits(scA[j] * acc[j]     + fc * bcA[j]);
      pk[4 + j] = f2bfbits(scB[j] * acc[4 + j] + fc * bcB[j]);
    }
  } else {
#pragma unroll
    for (int j = 0; j < 8; ++j) pk[j] = f2bfbits(acc[j]);
  }
  *reinterpret_cast<us8*>(aggB + (long)nq * DIM_H + c) = pk;
}

// ---------------- fused GIN MLP: 128-row blocks, global-W prefetch, 8-replica stats ----------
__global__ __launch_bounds__(256, 4)
void mlp_kernel(const unsigned short* __restrict__ A,
                const unsigned short* __restrict__ W1F, const float* __restrict__ b1,
                const unsigned short* __restrict__ W2F, const float* __restrict__ b2,
                unsigned short* __restrict__ Z, float* __restrict__ stats) {
  __shared__ __align__(16) unsigned short ybuf[128 * WPAD];   // 34816 B
  __shared__ float red[4][2][128];                            //  4096 B

  const int tid = threadIdx.x;
  const int wid = tid >> 6, lane = tid & 63;
  const int lr = lane & 15, lg = lane >> 4;
  const int row0 = blockIdx.x * 128;

  // A fragments (issue first; longest latency)
  bh8 afrag[2][4];
#pragma unroll
  for (int rt = 0; rt < 2; ++rt) {
    int row = row0 + wid * 32 + rt * 16 + lr;
    bool valid = row < N_NODES;
    const unsigned short* ap = A + (long)row * DIM_H;
#pragma unroll
    for (int kk = 0; kk < 4; ++kk) {
      us8 t = (us8)0;
      if (valid) t = *reinterpret_cast<const us8*>(ap + kk * 32 + 8 * lg);
      afrag[rt][kk] = __builtin_bit_cast(bh8, t);
    }
  }

  // preload all biases + first B tile
  float bias1[8], bias2[8];
#pragma unroll
  for (int n0 = 0; n0 < 8; ++n0) { bias1[n0] = b1[n0 * 16 + lr]; bias2[n0] = b2[n0 * 16 + lr]; }

  bh8 bnxt[4];
#pragma unroll
  for (int kk = 0; kk < 4; ++kk)
    bnxt[kk] = *reinterpret_cast<const bh8*>(&W1F[(kk << 9) + lane * 8]);

  // GEMM1 + bias + relu -> ybuf (B double-buffered)
#pragma unroll
  for (int n0 = 0; n0 < 8; ++n0) {
    bh8 bc[4];
#pragma unroll
    for (int kk = 0; kk < 4; ++kk) bc[kk] = bnxt[kk];
    if (n0 < 7) {
#pragma unroll
      for (int kk = 0; kk < 4; ++kk)
        bnxt[kk] = *reinterpret_cast<const bh8*>(&W1F[(((n0 + 1) * 4 + kk) << 9) + lane * 8]);
    }
    fl4 acc[2] = {{0,0,0,0},{0,0,0,0}};
#pragma unroll
    for (int kk = 0; kk < 4; ++kk) {
      acc[0] = __builtin_amdgcn_mfma_f32_16x16x32_bf16(afrag[0][kk], bc[kk], acc[0], 0, 0, 0);
      acc[1] = __builtin_amdgcn_mfma_f32_16x16x32_bf16(afrag[1][kk], bc[kk], acc[1], 0, 0, 0);
    }
#pragma unroll
    for (int rt = 0; rt < 2; ++rt)
#pragma unroll
      for (int r = 0; r < 4; ++r) {
        float v = acc[rt][r] + bias1[n0];
        v = v > 0.f ? v : 0.f;
        ybuf[(wid * 32 + rt * 16 + 4 * lg + r) * WPAD + n0 * 16 + lr] = f2bfbits(v);
      }
  }

  // prefetch first W2 tile (global; independent of LDS fences below)
#pragma unroll
  for (int kk = 0; kk < 4; ++kk)
    bnxt[kk] = *reinterpret_cast<const bh8*>(&W2F[(kk << 9) + lane * 8]);

  wave_lds_fence();          // ybuf writes visible to own wave

  // A2 fragments from ybuf (own-wave rows)
  bh8 a2[2][4];
#pragma unroll
  for (int rt = 0; rt < 2; ++rt)
#pragma unroll
    for (int kk = 0; kk < 4; ++kk)
      a2[rt][kk] = *reinterpret_cast<const bh8*>(
          &ybuf[(wid * 32 + rt * 16 + lr) * WPAD + kk * 32 + 8 * lg]);

  wave_lds_fence();          // a2 in regs before ybuf overwrite

  // GEMM2 + bias + relu -> ybuf (z), accumulate BN stats
#pragma unroll
  for (int n0 = 0; n0 < 8; ++n0) {
    bh8 bc[4];
#pragma unroll
    for (int kk = 0; kk < 4; ++kk) bc[kk] = bnxt[kk];
    if (n0 < 7) {
#pragma unroll
      for (int kk = 0; kk < 4; ++kk)
        bnxt[kk] = *reinterpret_cast<const bh8*>(&W2F[(((n0 + 1) * 4 + kk) << 9) + lane * 8]);
    }
    fl4 acc[2] = {{0,0,0,0},{0,0,0,0}};
#pragma unroll
    for (int kk = 0; kk < 4; ++kk) {
      acc[0] = __builtin_amdgcn_mfma_f32_16x16x32_bf16(a2[0][kk], bc[kk], acc[0], 0, 0, 0);
      acc[1] = __builtin_amdgcn_mfma_f32_16x16x32_bf16(a2[1][kk], bc[kk], acc[1], 0, 0, 0);
    }
    float sp = 0.f, qp = 0.f;
#pragma unroll
    for (int rt = 0; rt < 2; ++rt)
#pragma unroll
      for (int r = 0; r < 4; ++r) {
        int row = row0 + wid * 32 + rt * 16 + 4 * lg + r;
        float v = acc[rt][r] + bias2[n0];
        v = v > 0.f ? v : 0.f;
        ybuf[(wid * 32 + rt * 16 + 4 * lg + r) * WPAD + n0 * 16 + lr] = f2bfbits(v);
        if (row < N_NODES) { sp += v; qp += v * v; }
      }
    sp += __shfl_xor(sp, 16); sp += __shfl_xor(sp, 32);
    qp += __shfl_xor(qp, 16); qp += __shfl_xor(qp, 32);
    if (lg == 0) { red[wid][0][n0 * 16 + lr] = sp; red[wid][1][n0 * 16 + lr] = qp; }
  }

  wave_lds_fence();

  // per-wave coalesced z store (own 32 rows)
#pragma unroll
  for (int i = 0; i < 8; ++i) {
    int ch = i * 64 + lane;               // 0..511
    int r  = wid * 32 + (ch >> 4);
    int c8 = (ch & 15) << 3;
    int row = row0 + r;
    if (row < N_NODES)
      *reinterpret_cast<uint4*>(&Z[(long)row * DIM_H + c8]) =
          *reinterpret_cast<const uint4*>(&ybuf[r * WPAD + c8]);
  }

  __syncthreads();           // cross-wave stats reduce

  {
    int which = tid >> 7, cc = tid & 127;
    float v = red[0][which][cc] + red[1][which][cc] + red[2][which][cc] + red[3][which][cc];
    float* dst = stats + (blockIdx.x & 7) * 256;   // 8-replica split (contention /8)
    unsafeAtomicAdd(&dst[which * 128 + cc], v);
  }
}

// ---------------- head: BN-affine(sb) -> fc1 -> relu -> dropout(fp32 mask) -> fc2 -> log_softmax --
__global__ __launch_bounds__(256, 6)
void head_kernel(const unsigned short* __restrict__ Z, const float* __restrict__ sb,
                 const unsigned short* __restrict__ F1F, const float* __restrict__ fc1b,
                 const unsigned short* __restrict__ F2F, const float* __restrict__ fc2b,
                 const float* __restrict__ mask, float* __restrict__ out) {
  __shared__ __align__(16) unsigned short ybuf[64 * WPAD];    // 17408 B

  const int tid = threadIdx.x;
  const int wid = tid >> 6, lane = tid & 63;
  const int lr = lane & 15, lg = lane >> 4;
  const int row0 = blockIdx.x * 64;

  // biases preload
  float bias1[8], bias2[4];
#pragma unroll
  for (int n0 = 0; n0 < 8; ++n0) bias1[n0] = fc1b[n0 * 16 + lr];
#pragma unroll
  for (int n0 = 0; n0 < 4; ++n0) bias2[n0] = fc2b[n0 * 16 + lr];

  // A fragments: affine(z) in bf16 with precomputed sb
  bh8 afrag[4];
#pragma unroll
  for (int kk = 0; kk < 4; ++kk) {
    int k0 = kk * 32 + 8 * lg;
    fl4 s0  = *reinterpret_cast<const fl4*>(sb + k0);
    fl4 s1  = *reinterpret_cast<const fl4*>(sb + k0 + 4);
    fl4 bb0 = *reinterpret_cast<const fl4*>(sb + 128 + k0);
    fl4 bb1 = *reinterpret_cast<const fl4*>(sb + 128 + k0 + 4);
    int row = row0 + wid * 16 + lr;
    us8 t = (us8)0;
    if (row < N_NODES) {
      us8 zv = *reinterpret_cast<const us8*>(Z + (long)row * DIM_H + k0);
#pragma unroll
      for (int j = 0; j < 4; ++j) {
        t[j]     = f2bfbits(bf2f(zv[j])     * s0[j] + bb0[j]);
        t[4 + j] = f2bfbits(bf2f(zv[4 + j]) * s1[j] + bb1[j]);
      }
    }
    afrag[kk] = __builtin_bit_cast(bh8, t);
  }

  // GEMM1 + fc1b + relu + dropout(fp32 mask) -> ybuf (B double-buffered)
  bh8 bnxt[4];
#pragma unroll
  for (int kk = 0; kk < 4; ++kk)
    bnxt[kk] = *reinterpret_cast<const bh8*>(&F1F[(kk << 9) + lane * 8]);
#pragma unroll
  for (int n0 = 0; n0 < 8; ++n0) {
    bh8 bc[4];
#pragma unroll
    for (int kk = 0; kk < 4; ++kk) bc[kk] = bnxt[kk];
    if (n0 < 7) {
#pragma unroll
      for (int kk = 0; kk < 4; ++kk)
        bnxt[kk] = *reinterpret_cast<const bh8*>(&F1F[(((n0 + 1) * 4 + kk) << 9) + lane * 8]);
    }
    fl4 acc = {0.f, 0.f, 0.f, 0.f};
#pragma unroll
    for (int kk = 0; kk < 4; ++kk)
      acc = __builtin_amdgcn_mfma_f32_16x16x32_bf16(afrag[kk], bc[kk], acc, 0, 0, 0);
#pragma unroll
    for (int r = 0; r < 4; ++r) {
      int row = row0 + wid * 16 + 4 * lg + r;
      float v = acc[r] + bias1[n0];
      v = v > 0.f ? v : 0.f;
      float mk = (row < N_NODES) ? mask[(long)row * DIM_H + n0 * 16 + lr] : 0.f;
      ybuf[(wid * 16 + 4 * lg + r) * WPAD + n0 * 16 + lr] = f2bfbits(v * mk);
    }
  }

  // prefetch first F2 tile before fences
#pragma unroll
  for (int kk = 0; kk < 4; ++kk)
    bnxt[kk] = *reinterpret_cast<const bh8*>(&F2F[(kk << 9) + lane * 8]);

  wave_lds_fence();

  bh8 a2[4];
#pragma unroll
  for (int kk = 0; kk < 4; ++kk)
    a2[kk] = *reinterpret_cast<const bh8*>(
        &ybuf[(wid * 16 + lr) * WPAD + kk * 32 + 8 * lg]);

  // GEMM2 (N=64), B double-buffered
  fl4 acc2[4];
#pragma unroll
  for (int n0 = 0; n0 < 4; ++n0) {
    bh8 bc[4];
#pragma unroll
    for (int kk = 0; kk < 4; ++kk) bc[kk] = bnxt[kk];
    if (n0 < 3) {
#pragma unroll
      for (int kk = 0; kk < 4; ++kk)
        bnxt[kk] = *reinterpret_cast<const bh8*>(&F2F[(((n0 + 1) * 4 + kk) << 9) + lane * 8]);
    }
    acc2[n0] = (fl4){0.f, 0.f, 0.f, 0.f};
#pragma unroll
    for (int kk = 0; kk < 4; ++kk)
      acc2[n0] = __builtin_amdgcn_mfma_f32_16x16x32_bf16(a2[kk], bc[kk], acc2[n0], 0, 0, 0);
#pragma unroll
    for (int r = 0; r < 4; ++r) acc2[n0][r] += bias2[n0];
  }

  // log_softmax over 64 cols + store
#pragma unroll
  for (int r = 0; r < 4; ++r) {
    float m = fmaxf(fmaxf(acc2[0][r], acc2[1][r]), fmaxf(acc2[2][r], acc2[3][r]));
#pragma unroll
    for (int d = 1; d < 16; d <<= 1) m = fmaxf(m, __shfl_xor(m, d, 16));
    float se = 0.f;
#pragma unroll
    for (int n0 = 0; n0 < 4; ++n0) se += __expf(acc2[n0][r] - m);
#pragma unroll
    for (int d = 1; d < 16; d <<= 1) se += __shfl_xor(se, d, 16);
    float lse = m + __logf(se);
    int row = row0 + wid * 16 + 4 * lg + r;
    if (row < N_NODES) {
#pragma unroll
      for (int n0 = 0; n0 < 4; ++n0)
        out[(long)row * DIM_OUT + n0 * 16 + lr] = acc2[n0][r] - lse;
    }
  }
}

// ---------------- launcher ----------------
extern "C" void kernel_launch(void* const* d_in, const int* in_sizes, int n_in,
                              void* d_out, int out_size, void* d_ws, size_t ws_size,
                              hipStream_t stream) {
  const float* x      = (const float*)d_in[0];
  const int*   ei     = (const int*)d_in[1];
  const float* cw1    = (const float*)d_in[2];
  const float* cb1    = (const float*)d_in[3];
  const float* cw2    = (const float*)d_in[4];
  const float* cb2    = (const float*)d_in[5];
  const float* gamma  = (const float*)d_in[6];
  const float* beta   = (const float*)d_in[7];
  const float* fc1w   = (const float*)d_in[8];
  const float* fc1b   = (const float*)d_in[9];
  const float* fc2w   = (const float*)d_in[10];
  const float* fc2b   = (const float*)d_in[11];
  const float* mask   = (const float*)d_in[12];
  float* out = (float*)d_out;

  char* ws = (char*)d_ws;
  unsigned short* aggB  = (unsigned short*)ws;                 // 25,600,000 B
  unsigned short* Zb    = (unsigned short*)(ws + 25600000);    // 25,600,256 B (100001 rows; xB alias)
  unsigned short* W1F   = (unsigned short*)(ws + 51200256);    //     98,304 B
  unsigned short* W2F   = (unsigned short*)(ws + 51298560);    //     98,304 B
  unsigned short* F1F   = (unsigned short*)(ws + 51396864);    //     32,768 B
  unsigned short* F2F   = (unsigned short*)(ws + 51429632);    //     16,384 B
  float*          stats = (float*)(ws + 51446016);             //     24,576 B (3x8x256)
  int*            rowst = (int*)(ws + 51470592);               //    400,004 B
  int*            cursor= (int*)(ws + 51870596);               //    400,000 B
  int*            csr   = (int*)(ws + 52270596);               //  2,400,000 B
  int*            bsum  = (int*)(ws + 54670596);               //      1,564 B
  float*          sb    = (float*)(ws + 54672160);             //      3,072 B (3x256)
  if (ws_size < 54675232u) return;

  prep_kernel<<<NBLK, 256, 0, stream>>>(cw1, cw2, fc1w, fc2w, W1F, W2F, F1F, F2F,
                                        stats, cursor, Zb + (long)N_NODES * DIM_H);
  deg_xcast<<<12500, 256, 0, stream>>>(x, Zb, ei, cursor);     // xB -> Zb

  scanA<<<NBLK, 256, 0, stream>>>(cursor, rowst, bsum);
  scanC<<<NBLK, 256, 0, stream>>>(rowst, bsum, cursor);
  csr_fill<<<2344, 256, 0, stream>>>(ei, cursor, csr);

  // layer 0: gather bf16 x (in Zb) -> aggB; mlp overwrites Zb (xB dead)
  gather_h<0><<<GATHER_GRID, 256, 0, stream>>>(Zb, nullptr, rowst, csr, aggB);
  mlp_kernel<<<MLP_GRID, 256, 0, stream>>>(aggB, W1F, cb1, W2F, cb2, Zb, stats);
  bn_finalize<<<1, 128, 0, stream>>>(stats, gamma, beta, sb);

  // layer 1: uses sb0
  gather_h<1><<<GATHER_GRID, 256, 0, stream>>>(Zb, sb, rowst, csr, aggB);
  mlp_kernel<<<MLP_GRID, 256, 0, stream>>>(aggB, W1F + 16384, cb1 + 128, W2F + 16384,
                                           cb2 + 128, Zb, stats + 2048);
  bn_finalize<<<1, 128, 0, stream>>>(stats + 2048, gamma + 128, beta + 128, sb + 256);

  // layer 2: uses sb1
  gather_h<1><<<GATHER_GRID, 256, 0, stream>>>(Zb, sb + 256, rowst, csr, aggB);
  mlp_kernel<<<MLP_GRID, 256, 0, stream>>>(aggB, W1F + 32768, cb1 + 256, W2F + 32768,
                                           cb2 + 256, Zb, stats + 4096);
  bn_finalize<<<1, 128, 0, stream>>>(stats + 4096, gamma + 256, beta + 256, sb + 512);

  // head: uses sb2, reads fp32 mask directly
  head_kernel<<<GRID64_HEAD, 256, 0, stream>>>(Zb, sb + 512,
                                               F1F, fc1b, F2F, fc2b, mask, out);
}

// Round 25
// 256.540 us; speedup vs baseline: 1.0385x; 1.0385x over previous
//
#include <hip/hip_runtime.h>
#include <stdint.h>

#define N_NODES 100000
#define N_EDGES 600000
#define DIM_H   128
#define DIM_OUT 64
#define WPAD    136      // padded LDS row stride in ushort units (272B)
#define BN_EPS  1e-5f
#define NBLK    391      // ceil(N_NODES/256)
#define GRID64_HEAD 1563 // ceil(N_NODES/64)
#define MLP_GRID 782     // 128 rows/block
#define GATHER_GRID 6250 // 16 nodes/block (4 waves x 4 nodes)

typedef __attribute__((ext_vector_type(8))) __bf16        bh8;
typedef __attribute__((ext_vector_type(4))) float         fl4;
typedef __attribute__((ext_vector_type(8))) unsigned short us8;
typedef __attribute__((ext_vector_type(4))) unsigned short us4;

__device__ __forceinline__ unsigned short f2bfbits(float f) {
  unsigned int u = __builtin_bit_cast(unsigned int, f);
  u += 0x7fffu + ((u >> 16) & 1u);           // RNE
  return (unsigned short)(u >> 16);
}
__device__ __forceinline__ float bf2f(unsigned short b) {
  unsigned int u = ((unsigned int)b) << 16;
  return __builtin_bit_cast(float, u);
}
// in-wave LDS producer->consumer fence (lanes of the same wave only)
__device__ __forceinline__ void wave_lds_fence() {
  asm volatile("s_waitcnt lgkmcnt(0)" ::: "memory");
  __builtin_amdgcn_sched_barrier(0);
}

// ---------------- weight prep (fragment-linear layout) + zero stats/deg/dummy row ----------------
__global__ void prep_kernel(const float* __restrict__ cw1, const float* __restrict__ cw2,
                            const float* __restrict__ fc1w, const float* __restrict__ fc2w,
                            unsigned short* __restrict__ W1F, unsigned short* __restrict__ W2F,
                            unsigned short* __restrict__ F1F, unsigned short* __restrict__ F2F,
                            float* __restrict__ stats, int* __restrict__ deg,
                            unsigned short* __restrict__ zrow) {
  int t = blockIdx.x * 256 + threadIdx.x;
  if (t < 3 * 16384) {
    int l = t >> 14, o = t & 16383;
    int j = o & 7, lane = (o >> 3) & 63, kk = (o >> 9) & 3, n0 = o >> 11;
    int k = kk * 32 + ((lane >> 4) << 3) + j;
    int n = (n0 << 4) + (lane & 15);
    W1F[t] = f2bfbits(cw1[l * 16384 + k * 128 + n]);
    W2F[t] = f2bfbits(cw2[l * 16384 + k * 128 + n]);
  }
  if (t < 16384) {
    int o = t;
    int j = o & 7, lane = (o >> 3) & 63, kk = (o >> 9) & 3, n0 = o >> 11;
    int k = kk * 32 + ((lane >> 4) << 3) + j;
    int n = (n0 << 4) + (lane & 15);
    F1F[t] = f2bfbits(fc1w[k * 128 + n]);
  }
  if (t < 8192) {
    int o = t;
    int j = o & 7, lane = (o >> 3) & 63, kk = (o >> 9) & 3, n0 = o >> 11;
    int k = kk * 32 + ((lane >> 4) << 3) + j;
    int n = (n0 << 4) + (lane & 15);                 // n < 64
    F2F[t] = f2bfbits(fc2w[k * 64 + n]);
  }
  if (t < 6144)  stats[t] = 0.f;                     // 3 layers x 8 replicas x 256
  if (t < 128)   zrow[t] = 0;                        // dummy zero row at H[N_NODES]
  if (t < N_NODES) deg[t] = 0;
}

// ---------------- x->bf16 cast + degree count + dropout bitmask pack (R17 form) ----------------
__global__ void deg_xcast(const float* __restrict__ x, unsigned short* __restrict__ xB,
                          const int* __restrict__ ei, int* __restrict__ deg,
                          const float* __restrict__ mask, unsigned int* __restrict__ bmask) {
  int i = blockIdx.x * 256 + threadIdx.x;    // 3.2M fl4 chunks exactly
  fl4 v = reinterpret_cast<const fl4*>(x)[i];
  us4 p;
#pragma unroll
  for (int j = 0; j < 4; ++j) p[j] = f2bfbits(v[j]);
  reinterpret_cast<us4*>(xB)[i] = p;
  if (i < N_EDGES) atomicAdd(&deg[ei[N_EDGES + i]], 1);
  if (i < N_NODES * 4) {                     // one dword of bitmask = 32 cols
    const float* mp = mask + (long)i * 32;
    unsigned int b = 0;
#pragma unroll
    for (int j8 = 0; j8 < 8; ++j8) {
      fl4 mv = *reinterpret_cast<const fl4*>(mp + j8 * 4);
      b |= (mv[0] > 0.f ? 1u : 0u) << (j8 * 4 + 0);
      b |= (mv[1] > 0.f ? 1u : 0u) << (j8 * 4 + 1);
      b |= (mv[2] > 0.f ? 1u : 0u) << (j8 * 4 + 2);
      b |= (mv[3] > 0.f ? 1u : 0u) << (j8 * 4 + 3);
    }
    bmask[i] = b;
  }
}

// ---------------- CSR build ----------------
__global__ void scanA(const int* __restrict__ deg, int* __restrict__ rowstart,
                      int* __restrict__ bsum) {
  __shared__ int s[256];
  int t = threadIdx.x, i = blockIdx.x * 256 + t;
  int v = (i < N_NODES) ? deg[i] : 0;
  s[t] = v;
  __syncthreads();
#pragma unroll
  for (int off = 1; off < 256; off <<= 1) {
    int u = (t >= off) ? s[t - off] : 0;
    __syncthreads();
    s[t] += u;
    __syncthreads();
  }
  if (i < N_NODES) rowstart[i] = s[t] - v;
  if (t == 0) bsum[blockIdx.x] = s[255];
}

// scanC with inline block-offset computation
__global__ void scanC(int* __restrict__ rowstart, const int* __restrict__ bsum,
                      int* __restrict__ cursor) {
  __shared__ int sred[256];
  int b = blockIdx.x, t = threadIdx.x;
  int partial = 0;
  for (int j = t; j < b; j += 256) partial += bsum[j];
  sred[t] = partial;
  __syncthreads();
#pragma unroll
  for (int off = 128; off > 0; off >>= 1) {
    if (t < off) sred[t] += sred[t + off];
    __syncthreads();
  }
  int boffb = sred[0];
  int i = b * 256 + t;
  if (i < N_NODES) {
    int v = rowstart[i] + boffb;
    rowstart[i] = v;
    cursor[i] = v;
  }
  if (i == 0) rowstart[N_NODES] = N_EDGES;
}

__global__ void csr_fill(const int* __restrict__ ei, int* __restrict__ cursor,
                         int* __restrict__ csr_src) {
  int e = blockIdx.x * 256 + threadIdx.x;
  if (e < N_EDGES) {
    int pos = atomicAdd(&cursor[ei[N_EDGES + e]], 1);
    csr_src[pos] = ei[e];
  }
}

// ---------------- BN finalize (sums 8 stat replicas) ----------------
__global__ void bn_finalize(const float* __restrict__ stats, const float* __restrict__ gamma,
                            const float* __restrict__ beta, float* __restrict__ sb) {
  int c = threadIdx.x;
  float s = 0.f, ss = 0.f;
#pragma unroll
  for (int r = 0; r < 8; ++r) {
    s  += stats[r * 256 + c];
    ss += stats[r * 256 + 128 + c];
  }
  const float inv_n = 1.0f / (float)N_NODES;
  float mean = s * inv_n;
  float var  = ss * inv_n - mean * mean;
  float sc = gamma[c] * rsqrtf(var + BN_EPS);
  sb[c] = sc;
  sb[128 + c] = beta[c] - mean * sc;
}

// ---------------- gather: FOUR nodes per wave, one per quarter; no cross-quarter reduce ----------
template <int AFFINE>
__global__ __launch_bounds__(256)
void gather_h(const unsigned short* __restrict__ H, const float* __restrict__ sb,
              const int* __restrict__ rowstart, const int* __restrict__ csr,
              unsigned short* __restrict__ aggB) {
  int wbase = (blockIdx.x * 4 + (threadIdx.x >> 6)) * 4;  // 6250*4*4 == N_NODES exactly
  int lane = threadIdx.x & 63;
  int q = lane >> 4, lc = lane & 15;
  int c = lc * 8;                        // 8 bf16 cols/lane; 16 lanes cover the row

  fl4 scA, scB, bcA, bcB;
  if (AFFINE) {
    scA = *reinterpret_cast<const fl4*>(sb + c);
    scB = *reinterpret_cast<const fl4*>(sb + c + 4);
    bcA = *reinterpret_cast<const fl4*>(sb + 128 + c);
    bcB = *reinterpret_cast<const fl4*>(sb + 128 + c + 4);
  }

  int nq = wbase + q;                    // this quarter's node (uniform within quarter)
  int rs = rowstart[nq], re = rowstart[nq + 1];
  int cnt = re - rs + 1;                 // {self} + neighbors
  int cmax = cnt;                        // wave-uniform loop bound = max over 4 quarters
  cmax = max(cmax, __shfl_xor(cmax, 16));
  cmax = max(cmax, __shfl_xor(cmax, 32));

  float acc[8] = {0.f, 0.f, 0.f, 0.f, 0.f, 0.f, 0.f, 0.f};

  for (int base = 0; base < cmax; base += 16) {
    int item = base + lc;
    int myidx = (item == 0) ? nq
              : ((item < cnt) ? csr[rs + item - 1] : N_NODES);  // dummy zero row
    int lim = cmax - base; if (lim > 16) lim = 16;
    for (int m = 0; m < lim; m += 4) {   // 4 rows in flight per quarter (16 per wave)
      int i0 = __shfl(myidx, (q << 4) + m);
      int i1 = __shfl(myidx, (q << 4) + m + 1);
      int i2 = __shfl(myidx, (q << 4) + m + 2);
      int i3 = __shfl(myidx, (q << 4) + m + 3);
      us8 r0 = *reinterpret_cast<const us8*>(H + (long)i0 * DIM_H + c);
      us8 r1 = *reinterpret_cast<const us8*>(H + (long)i1 * DIM_H + c);
      us8 r2 = *reinterpret_cast<const us8*>(H + (long)i2 * DIM_H + c);
      us8 r3 = *reinterpret_cast<const us8*>(H + (long)i3 * DIM_H + c);
#pragma unroll
      for (int j = 0; j < 8; ++j)
        acc[j] += (bf2f(r0[j]) + bf2f(r1[j])) + (bf2f(r2[j]) + bf2f(r3[j]));
    }
  }

  // direct store: every lane stores its 8 cols of its quarter's node
  us8 pk;
  if (AFFINE) {
    float fc = (float)cnt;
#pragma unroll
    for (int j = 0; j < 4; ++j) {
      pk[j]     = f2bfbits(scA[j] * acc[j]     + fc * bcA[j]);
      pk[4 + j] = f2bfbits(scB[j] * acc[4 + j] + fc * bcB[j]);
    }
  } else {
#pragma unroll
    for (int j = 0; j < 8; ++j) pk[j] = f2bfbits(acc[j]);
  }
  *reinterpret_cast<us8*>(aggB + (long)nq * DIM_H + c) = pk;
}

// ---------------- fused GIN MLP: 128-row blocks, global-W prefetch, 8-replica stats ----------
__global__ __launch_bounds__(256, 4)
void mlp_kernel(const unsigned short* __restrict__ A,
                const unsigned short* __restrict__ W1F, const float* __restrict__ b1,
                const unsigned short* __restrict__ W2F, const float* __restrict__ b2,
                unsigned short* __restrict__ Z, float* __restrict__ stats) {
  __shared__ __align__(16) unsigned short ybuf[128 * WPAD];   // 34816 B
  __shared__ float red[4][2][128];                            //  4096 B

  const int tid = threadIdx.x;
  const int wid = tid >> 6, lane = tid & 63;
  const int lr = lane & 15, lg = lane >> 4;
  const int row0 = blockIdx.x * 128;

  // A fragments (issue first; longest latency)
  bh8 afrag[2][4];
#pragma unroll
  for (int rt = 0; rt < 2; ++rt) {
    int row = row0 + wid * 32 + rt * 16 + lr;
    bool valid = row < N_NODES;
    const unsigned short* ap = A + (long)row * DIM_H;
#pragma unroll
    for (int kk = 0; kk < 4; ++kk) {
      us8 t = (us8)0;
      if (valid) t = *reinterpret_cast<const us8*>(ap + kk * 32 + 8 * lg);
      afrag[rt][kk] = __builtin_bit_cast(bh8, t);
    }
  }

  // preload all biases + first B tile
  float bias1[8], bias2[8];
#pragma unroll
  for (int n0 = 0; n0 < 8; ++n0) { bias1[n0] = b1[n0 * 16 + lr]; bias2[n0] = b2[n0 * 16 + lr]; }

  bh8 bnxt[4];
#pragma unroll
  for (int kk = 0; kk < 4; ++kk)
    bnxt[kk] = *reinterpret_cast<const bh8*>(&W1F[(kk << 9) + lane * 8]);

  // GEMM1 + bias + relu -> ybuf (B double-buffered)
#pragma unroll
  for (int n0 = 0; n0 < 8; ++n0) {
    bh8 bc[4];
#pragma unroll
    for (int kk = 0; kk < 4; ++kk) bc[kk] = bnxt[kk];
    if (n0 < 7) {
#pragma unroll
      for (int kk = 0; kk < 4; ++kk)
        bnxt[kk] = *reinterpret_cast<const bh8*>(&W1F[(((n0 + 1) * 4 + kk) << 9) + lane * 8]);
    }
    fl4 acc[2] = {{0,0,0,0},{0,0,0,0}};
#pragma unroll
    for (int kk = 0; kk < 4; ++kk) {
      acc[0] = __builtin_amdgcn_mfma_f32_16x16x32_bf16(afrag[0][kk], bc[kk], acc[0], 0, 0, 0);
      acc[1] = __builtin_amdgcn_mfma_f32_16x16x32_bf16(afrag[1][kk], bc[kk], acc[1], 0, 0, 0);
    }
#pragma unroll
    for (int rt = 0; rt < 2; ++rt)
#pragma unroll
      for (int r = 0; r < 4; ++r) {
        float v = acc[rt][r] + bias1[n0];
        v = v > 0.f ? v : 0.f;
        ybuf[(wid * 32 + rt * 16 + 4 * lg + r) * WPAD + n0 * 16 + lr] = f2bfbits(v);
      }
  }

  // prefetch first W2 tile (global; independent of LDS fences below)
#pragma unroll
  for (int kk = 0; kk < 4; ++kk)
    bnxt[kk] = *reinterpret_cast<const bh8*>(&W2F[(kk << 9) + lane * 8]);

  wave_lds_fence();          // ybuf writes visible to own wave

  // A2 fragments from ybuf (own-wave rows)
  bh8 a2[2][4];
#pragma unroll
  for (int rt = 0; rt < 2; ++rt)
#pragma unroll
    for (int kk = 0; kk < 4; ++kk)
      a2[rt][kk] = *reinterpret_cast<const bh8*>(
          &ybuf[(wid * 32 + rt * 16 + lr) * WPAD + kk * 32 + 8 * lg]);

  wave_lds_fence();          // a2 in regs before ybuf overwrite

  // GEMM2 + bias + relu -> ybuf (z), accumulate BN stats
#pragma unroll
  for (int n0 = 0; n0 < 8; ++n0) {
    bh8 bc[4];
#pragma unroll
    for (int kk = 0; kk < 4; ++kk) bc[kk] = bnxt[kk];
    if (n0 < 7) {
#pragma unroll
      for (int kk = 0; kk < 4; ++kk)
        bnxt[kk] = *reinterpret_cast<const bh8*>(&W2F[(((n0 + 1) * 4 + kk) << 9) + lane * 8]);
    }
    fl4 acc[2] = {{0,0,0,0},{0,0,0,0}};
#pragma unroll
    for (int kk = 0; kk < 4; ++kk) {
      acc[0] = __builtin_amdgcn_mfma_f32_16x16x32_bf16(a2[0][kk], bc[kk], acc[0], 0, 0, 0);
      acc[1] = __builtin_amdgcn_mfma_f32_16x16x32_bf16(a2[1][kk], bc[kk], acc[1], 0, 0, 0);
    }
    float sp = 0.f, qp = 0.f;
#pragma unroll
    for (int rt = 0; rt < 2; ++rt)
#pragma unroll
      for (int r = 0; r < 4; ++r) {
        int row = row0 + wid * 32 + rt * 16 + 4 * lg + r;
        float v = acc[rt][r] + bias2[n0];
        v = v > 0.f ? v : 0.f;
        ybuf[(wid * 32 + rt * 16 + 4 * lg + r) * WPAD + n0 * 16 + lr] = f2bfbits(v);
        if (row < N_NODES) { sp += v; qp += v * v; }
      }
    sp += __shfl_xor(sp, 16); sp += __shfl_xor(sp, 32);
    qp += __shfl_xor(qp, 16); qp += __shfl_xor(qp, 32);
    if (lg == 0) { red[wid][0][n0 * 16 + lr] = sp; red[wid][1][n0 * 16 + lr] = qp; }
  }

  wave_lds_fence();

  // per-wave coalesced z store (own 32 rows)
#pragma unroll
  for (int i = 0; i < 8; ++i) {
    int ch = i * 64 + lane;               // 0..511
    int r  = wid * 32 + (ch >> 4);
    int c8 = (ch & 15) << 3;
    int row = row0 + r;
    if (row < N_NODES)
      *reinterpret_cast<uint4*>(&Z[(long)row * DIM_H + c8]) =
          *reinterpret_cast<const uint4*>(&ybuf[r * WPAD + c8]);
  }

  __syncthreads();           // cross-wave stats reduce

  {
    int which = tid >> 7, cc = tid & 127;
    float v = red[0][which][cc] + red[1][which][cc] + red[2][which][cc] + red[3][which][cc];
    float* dst = stats + (blockIdx.x & 7) * 256;   // 8-replica split (contention /8)
    unsafeAtomicAdd(&dst[which * 128 + cc], v);
  }
}

// ---------------- head: BN-affine(sb) -> fc1 -> relu -> dropout(bitmask) -> fc2 -> log_softmax --
__global__ __launch_bounds__(256, 6)
void head_kernel(const unsigned short* __restrict__ Z, const float* __restrict__ sb,
                 const unsigned short* __restrict__ F1F, const float* __restrict__ fc1b,
                 const unsigned short* __restrict__ F2F, const float* __restrict__ fc2b,
                 const unsigned int* __restrict__ bmask, float* __restrict__ out) {
  __shared__ __align__(16) unsigned short ybuf[64 * WPAD];    // 17408 B

  const int tid = threadIdx.x;
  const int wid = tid >> 6, lane = tid & 63;
  const int lr = lane & 15, lg = lane >> 4;
  const int row0 = blockIdx.x * 64;

  // dropout bitmask for this lane's 4 output rows (128 bits each)
  unsigned int bw[4][4];
#pragma unroll
  for (int r = 0; r < 4; ++r) {
    int row = row0 + wid * 16 + 4 * lg + r;
    if (row < N_NODES) {
      uint4 t = *reinterpret_cast<const uint4*>(bmask + (long)row * 4);
      bw[r][0] = t.x; bw[r][1] = t.y; bw[r][2] = t.z; bw[r][3] = t.w;
    } else {
      bw[r][0] = bw[r][1] = bw[r][2] = bw[r][3] = 0u;
    }
  }

  // biases preload
  float bias1[8], bias2[4];
#pragma unroll
  for (int n0 = 0; n0 < 8; ++n0) bias1[n0] = fc1b[n0 * 16 + lr];
#pragma unroll
  for (int n0 = 0; n0 < 4; ++n0) bias2[n0] = fc2b[n0 * 16 + lr];

  // A fragments: affine(z) in bf16 with precomputed sb
  bh8 afrag[4];
#pragma unroll
  for (int kk = 0; kk < 4; ++kk) {
    int k0 = kk * 32 + 8 * lg;
    fl4 s0  = *reinterpret_cast<const fl4*>(sb + k0);
    fl4 s1  = *reinterpret_cast<const fl4*>(sb + k0 + 4);
    fl4 bb0 = *reinterpret_cast<const fl4*>(sb + 128 + k0);
    fl4 bb1 = *reinterpret_cast<const fl4*>(sb + 128 + k0 + 4);
    int row = row0 + wid * 16 + lr;
    us8 t = (us8)0;
    if (row < N_NODES) {
      us8 zv = *reinterpret_cast<const us8*>(Z + (long)row * DIM_H + k0);
#pragma unroll
      for (int j = 0; j < 4; ++j) {
        t[j]     = f2bfbits(bf2f(zv[j])     * s0[j] + bb0[j]);
        t[4 + j] = f2bfbits(bf2f(zv[4 + j]) * s1[j] + bb1[j]);
      }
    }
    afrag[kk] = __builtin_bit_cast(bh8, t);
  }

  // GEMM1 + fc1b + relu + dropout -> ybuf (B double-buffered)
  bh8 bnxt[4];
#pragma unroll
  for (int kk = 0; kk < 4; ++kk)
    bnxt[kk] = *reinterpret_cast<const bh8*>(&F1F[(kk << 9) + lane * 8]);
#pragma unroll
  for (int n0 = 0; n0 < 8; ++n0) {
    bh8 bc[4];
#pragma unroll
    for (int kk = 0; kk < 4; ++kk) bc[kk] = bnxt[kk];
    if (n0 < 7) {
#pragma unroll
      for (int kk = 0; kk < 4; ++kk)
        bnxt[kk] = *reinterpret_cast<const bh8*>(&F1F[(((n0 + 1) * 4 + kk) << 9) + lane * 8]);
    }
    fl4 acc = {0.f, 0.f, 0.f, 0.f};
#pragma unroll
    for (int kk = 0; kk < 4; ++kk)
      acc = __builtin_amdgcn_mfma_f32_16x16x32_bf16(afrag[kk], bc[kk], acc, 0, 0, 0);
#pragma unroll
    for (int r = 0; r < 4; ++r) {
      float v = acc[r] + bias1[n0];
      v = v > 0.f ? v : 0.f;
      float mk = ((bw[r][n0 >> 1] >> (((n0 & 1) << 4) + lr)) & 1u) ? 2.0f : 0.0f;
      ybuf[(wid * 16 + 4 * lg + r) * WPAD + n0 * 16 + lr] = f2bfbits(v * mk);
    }
  }

  // prefetch first F2 tile before fences
#pragma unroll
  for (int kk = 0; kk < 4; ++kk)
    bnxt[kk] = *reinterpret_cast<const bh8*>(&F2F[(kk << 9) + lane * 8]);

  wave_lds_fence();

  bh8 a2[4];
#pragma unroll
  for (int kk = 0; kk < 4; ++kk)
    a2[kk] = *reinterpret_cast<const bh8*>(
        &ybuf[(wid * 16 + lr) * WPAD + kk * 32 + 8 * lg]);

  // GEMM2 (N=64), B double-buffered
  fl4 acc2[4];
#pragma unroll
  for (int n0 = 0; n0 < 4; ++n0) {
    bh8 bc[4];
#pragma unroll
    for (int kk = 0; kk < 4; ++kk) bc[kk] = bnxt[kk];
    if (n0 < 3) {
#pragma unroll
      for (int kk = 0; kk < 4; ++kk)
        bnxt[kk] = *reinterpret_cast<const bh8*>(&F2F[(((n0 + 1) * 4 + kk) << 9) + lane * 8]);
    }
    acc2[n0] = (fl4){0.f, 0.f, 0.f, 0.f};
#pragma unroll
    for (int kk = 0; kk < 4; ++kk)
      acc2[n0] = __builtin_amdgcn_mfma_f32_16x16x32_bf16(a2[kk], bc[kk], acc2[n0], 0, 0, 0);
#pragma unroll
    for (int r = 0; r < 4; ++r) acc2[n0][r] += bias2[n0];
  }

  // log_softmax over 64 cols + store
#pragma unroll
  for (int r = 0; r < 4; ++r) {
    float m = fmaxf(fmaxf(acc2[0][r], acc2[1][r]), fmaxf(acc2[2][r], acc2[3][r]));
#pragma unroll
    for (int d = 1; d < 16; d <<= 1) m = fmaxf(m, __shfl_xor(m, d, 16));
    float se = 0.f;
#pragma unroll
    for (int n0 = 0; n0 < 4; ++n0) se += __expf(acc2[n0][r] - m);
#pragma unroll
    for (int d = 1; d < 16; d <<= 1) se += __shfl_xor(se, d, 16);
    float lse = m + __logf(se);
    int row = row0 + wid * 16 + 4 * lg + r;
    if (row < N_NODES) {
#pragma unroll
      for (int n0 = 0; n0 < 4; ++n0)
        out[(long)row * DIM_OUT + n0 * 16 + lr] = acc2[n0][r] - lse;
    }
  }
}

// ---------------- launcher ----------------
extern "C" void kernel_launch(void* const* d_in, const int* in_sizes, int n_in,
                              void* d_out, int out_size, void* d_ws, size_t ws_size,
                              hipStream_t stream) {
  const float* x      = (const float*)d_in[0];
  const int*   ei     = (const int*)d_in[1];
  const float* cw1    = (const float*)d_in[2];
  const float* cb1    = (const float*)d_in[3];
  const float* cw2    = (const float*)d_in[4];
  const float* cb2    = (const float*)d_in[5];
  const float* gamma  = (const float*)d_in[6];
  const float* beta   = (const float*)d_in[7];
  const float* fc1w   = (const float*)d_in[8];
  const float* fc1b   = (const float*)d_in[9];
  const float* fc2w   = (const float*)d_in[10];
  const float* fc2b   = (const float*)d_in[11];
  const float* mask   = (const float*)d_in[12];
  float* out = (float*)d_out;

  char* ws = (char*)d_ws;
  unsigned short* aggB  = (unsigned short*)ws;                 // 25,600,000 B
  unsigned short* Zb    = (unsigned short*)(ws + 25600000);    // 25,600,256 B (100001 rows; xB alias)
  unsigned short* W1F   = (unsigned short*)(ws + 51200256);    //     98,304 B
  unsigned short* W2F   = (unsigned short*)(ws + 51298560);    //     98,304 B
  unsigned short* F1F   = (unsigned short*)(ws + 51396864);    //     32,768 B
  unsigned short* F2F   = (unsigned short*)(ws + 51429632);    //     16,384 B
  float*          stats = (float*)(ws + 51446016);             //     24,576 B (3x8x256)
  int*            rowst = (int*)(ws + 51470592);               //    400,004 B
  int*            cursor= (int*)(ws + 51870596);               //    400,000 B
  int*            csr   = (int*)(ws + 52270596);               //  2,400,000 B
  int*            bsum  = (int*)(ws + 54670596);               //      1,564 B
  unsigned int*   bmask = (unsigned int*)(ws + 54672160);      //  1,600,000 B
  float*          sb    = (float*)(ws + 56272160);             //      3,072 B (3x256)
  if (ws_size < 56275232u) return;

  prep_kernel<<<NBLK, 256, 0, stream>>>(cw1, cw2, fc1w, fc2w, W1F, W2F, F1F, F2F,
                                        stats, cursor, Zb + (long)N_NODES * DIM_H);
  deg_xcast<<<12500, 256, 0, stream>>>(x, Zb, ei, cursor, mask, bmask); // xB -> Zb

  scanA<<<NBLK, 256, 0, stream>>>(cursor, rowst, bsum);
  scanC<<<NBLK, 256, 0, stream>>>(rowst, bsum, cursor);
  csr_fill<<<2344, 256, 0, stream>>>(ei, cursor, csr);

  // layer 0: gather bf16 x (in Zb) -> aggB; mlp overwrites Zb (xB dead)
  gather_h<0><<<GATHER_GRID, 256, 0, stream>>>(Zb, nullptr, rowst, csr, aggB);
  mlp_kernel<<<MLP_GRID, 256, 0, stream>>>(aggB, W1F, cb1, W2F, cb2, Zb, stats);
  bn_finalize<<<1, 128, 0, stream>>>(stats, gamma, beta, sb);

  // layer 1: uses sb0
  gather_h<1><<<GATHER_GRID, 256, 0, stream>>>(Zb, sb, rowst, csr, aggB);
  mlp_kernel<<<MLP_GRID, 256, 0, stream>>>(aggB, W1F + 16384, cb1 + 128, W2F + 16384,
                                           cb2 + 128, Zb, stats + 2048);
  bn_finalize<<<1, 128, 0, stream>>>(stats + 2048, gamma + 128, beta + 128, sb + 256);

  // layer 2: uses sb1
  gather_h<1><<<GATHER_GRID, 256, 0, stream>>>(Zb, sb + 256, rowst, csr, aggB);
  mlp_kernel<<<MLP_GRID, 256, 0, stream>>>(aggB, W1F + 32768, cb1 + 256, W2F + 32768,
                                           cb2 + 256, Zb, stats + 4096);
  bn_finalize<<<1, 128, 0, stream>>>(stats + 4096, gamma + 256, beta + 256, sb + 512);

  // head: uses sb2
  head_kernel<<<GRID64_HEAD, 256, 0, stream>>>(Zb, sb + 512,
                                               F1F, fc1b, F2F, fc2b, bmask, out);
}